// Round 5
// baseline (496.100 us; speedup 1.0000x reference)
//
#include <hip/hip_runtime.h>
#include <hip/hip_bf16.h>

// PLIF forward: v += x_t; spike = (v - 1 > 0); v -= spike * 1.0
// x: [T=16, N] fp32, out: spikes [T=16, N] fp32. N = B*C*H*W = 4,194,304.
//
// One-shot kernel, one thread per 4 contiguous spatial elements.
// All 16 timestep loads are issued back-to-back and PINNED before any
// compute via __builtin_amdgcn_sched_barrier(0) — round 4 showed the
// compiler otherwise collapses the load cluster (VGPR=36) and serializes
// on per-use vmcnt waits (2.1 TB/s). With the fence: 16 outstanding
// global_load_dwordx4 per wave (16 KiB), ~84 VGPR -> 6 waves/SIMD, and
// compute of plane t waits only on load t (in-order consumption overlaps
// the remaining returns).
//
// Loads regular (x is L3-resident from the harness d_in restore; FETCH_SIZE
// shows only half the input comes from HBM). Stores nontemporal (out is
// touch-once; don't let it evict x from L3).

#ifndef PLIF_T
#define PLIF_T 16
#endif

typedef float f32x4 __attribute__((ext_vector_type(4)));

__global__ __launch_bounds__(256) void plif_fwd_kernel(
    const f32x4* __restrict__ x, f32x4* __restrict__ out, int n4) {
    const int i = blockIdx.x * blockDim.x + threadIdx.x;
    if (i >= n4) return;

    // Phase 1: issue all T loads back-to-back. Compile-time indices only
    // (rule #20) so xt[] lives entirely in VGPRs.
    f32x4 xt[PLIF_T];
    #pragma unroll
    for (int t = 0; t < PLIF_T; ++t) {
        xt[t] = x[(size_t)t * (size_t)n4 + (size_t)i];
    }
    // Hard scheduling fence: nothing below may be hoisted above, no load
    // above may sink below. Guarantees the 16-load cluster in the .s.
    __builtin_amdgcn_sched_barrier(0);

    // Phase 2: serial recurrence; consumes loads in issue order, so the
    // compiler emits s_waitcnt vmcnt(15), vmcnt(14), ... per plane.
    f32x4 v = (f32x4)(0.f, 0.f, 0.f, 0.f);
    #pragma unroll
    for (int t = 0; t < PLIF_T; ++t) {
        v += xt[t];

        f32x4 s;
        s.x = (v.x > 1.0f) ? 1.0f : 0.0f;
        s.y = (v.y > 1.0f) ? 1.0f : 0.0f;
        s.z = (v.z > 1.0f) ? 1.0f : 0.0f;
        s.w = (v.w > 1.0f) ? 1.0f : 0.0f;

        v -= s;

        __builtin_nontemporal_store(s, &out[(size_t)t * (size_t)n4 + (size_t)i]);
    }
}

extern "C" void kernel_launch(void* const* d_in, const int* in_sizes, int n_in,
                              void* d_out, int out_size, void* d_ws, size_t ws_size,
                              hipStream_t stream) {
    const float* x = (const float*)d_in[0];
    float* out = (float*)d_out;

    const int total = in_sizes[0];          // T * N
    const int n = total / PLIF_T;           // spatial elements per timestep
    const int n4 = n / 4;                   // float4 groups per timestep

    const int block = 256;
    const int grid = (n4 + block - 1) / block;   // 4096 for reference shape

    plif_fwd_kernel<<<grid, block, 0, stream>>>(
        (const f32x4*)x, (f32x4*)out, n4);
}

// Round 11
// 470.248 us; speedup vs baseline: 1.0550x; 1.0550x over previous
//
#include <hip/hip_runtime.h>
#include <hip/hip_bf16.h>

// PLIF forward: v += x_t; spike = (v - 1 > 0); v -= spike * 1.0
// x: [T=16, N] fp32, out: spikes [T=16, N] fp32. N = B*C*H*W = 4,194,304.
//
// Round 5 showed the compiler defeats both source-level load hoisting AND
// __builtin_amdgcn_sched_barrier(0): VGPR stayed 36 (16 float4 loads in
// flight need >=64), i.e. the load cluster was collapsed to a ~4-deep
// rolling window -> one HBM latency per window -> 2.1 TB/s.
//
// This version forces the cluster with inline asm:
//  - 16 asm volatile global_load_dwordx4 with distinct "=v" outputs:
//    mutually ordered, all 16 results live simultaneously (64 VGPRs),
//    16 KiB in flight per wave.
//  - consumption via tied-operand s_waitcnt: "+v"(xt[t]) makes every use
//    of xt[t] data-dependent on the waitcnt asm (rule #18 via data dep).
//  - vmcnt(15-t) before consuming load t: loads retire in issue order, so
//    outstanding <= 15-t guarantees loads 0..t have returned, regardless
//    of how many compiler-placed stores are also in the vmcnt FIFO.
//  - stores remain compiler-managed nontemporal (its own waitcnt model
//    stays conservative-safe: my extra outstanding loads only make its
//    waits stricter, never looser).

#ifndef PLIF_T
#define PLIF_T 16
#endif

typedef float f32x4 __attribute__((ext_vector_type(4)));

__global__ __launch_bounds__(256) void plif_fwd_kernel(
    const f32x4* __restrict__ x, f32x4* __restrict__ out, int n4) {
    const int i = blockIdx.x * blockDim.x + threadIdx.x;
    if (i >= n4) return;

    const size_t stride = (size_t)n4;
    const f32x4* p0 = x + (size_t)i;

    // Phase 1: 16 loads, forced back-to-back, all results live.
    f32x4 xt[PLIF_T];
    #pragma unroll
    for (int t = 0; t < PLIF_T; ++t) {
        const f32x4* addr = p0 + (size_t)t * stride;
        asm volatile("global_load_dwordx4 %0, %1, off"
                     : "=v"(xt[t])
                     : "v"(addr));
    }

    // Phase 2: serial recurrence, consuming loads in issue order.
    f32x4 v = (f32x4)(0.f, 0.f, 0.f, 0.f);
    #pragma unroll
    for (int t = 0; t < PLIF_T; ++t) {
        // Wait until at most (15-t) VMEM ops outstanding -> loads 0..t done.
        // Tied operand makes all later uses of xt[t] depend on this asm.
        asm volatile("s_waitcnt vmcnt(%c1)"
                     : "+v"(xt[t])
                     : "i"(PLIF_T - 1 - t));

        v += xt[t];

        f32x4 s;
        s.x = (v.x > 1.0f) ? 1.0f : 0.0f;
        s.y = (v.y > 1.0f) ? 1.0f : 0.0f;
        s.z = (v.z > 1.0f) ? 1.0f : 0.0f;
        s.w = (v.w > 1.0f) ? 1.0f : 0.0f;

        v -= s;

        __builtin_nontemporal_store(s, &out[(size_t)t * stride + (size_t)i]);
    }
}

extern "C" void kernel_launch(void* const* d_in, const int* in_sizes, int n_in,
                              void* d_out, int out_size, void* d_ws, size_t ws_size,
                              hipStream_t stream) {
    const float* x = (const float*)d_in[0];
    float* out = (float*)d_out;

    const int total = in_sizes[0];          // T * N
    const int n = total / PLIF_T;           // spatial elements per timestep
    const int n4 = n / 4;                   // float4 groups per timestep

    const int block = 256;
    const int grid = (n4 + block - 1) / block;   // 4096 for reference shape

    plif_fwd_kernel<<<grid, block, 0, stream>>>(
        (const f32x4*)x, (f32x4*)out, n4);
}

// Round 12
// 451.836 us; speedup vs baseline: 1.0980x; 1.0407x over previous
//
#include <hip/hip_runtime.h>
#include <hip/hip_bf16.h>

// PLIF forward: v += x_t; spike = (v - 1 > 0); v -= spike * 1.0
// x: [T=16, N] fp32, out: spikes [T=16, N] fp32. N = B*C*H*W = 4,194,304.
//
// Round-11 post-mortem: four different schedules (naive, SW-pipelined,
// sched_barrier, forced inline-asm load cluster) all land at ~190 us /
// 2.1 TB/s -> NOT latency-limited (per-CU in-flight bytes ~80 KB >> 9 KB
// Little's-law requirement even with a 4-deep window). The only variant
// that beat the harness's 165-us fill dispatches was Round 3, whose sole
// distinguishing feature was NONTEMPORAL LOADS. Theory: 32 concurrent
// 16-MiB-stride streams thrash L2/L3 set allocation; nt loads skip cache
// allocation (still hit L3 when present - FETCH_SIZE stays ~134 MB of the
// 268 MB input) and avoid the thrash. This reverts to the Round-3 config
// exactly: prefetch all 16 planes, nt loads + nt stores, one-shot grid.

#ifndef PLIF_T
#define PLIF_T 16
#endif

typedef float f32x4 __attribute__((ext_vector_type(4)));

__global__ __launch_bounds__(256) void plif_fwd_kernel(
    const f32x4* __restrict__ x, f32x4* __restrict__ out, int n4) {
    int i = blockIdx.x * blockDim.x + threadIdx.x;
    if (i >= n4) return;

    // Phase 1: issue all T loads back-to-back (independent addresses).
    // Compile-time indices only -> stays in VGPRs, no scratch.
    f32x4 xt[PLIF_T];
    #pragma unroll
    for (int t = 0; t < PLIF_T; ++t) {
        xt[t] = __builtin_nontemporal_load(&x[(size_t)t * (size_t)n4 + (size_t)i]);
    }

    // Phase 2: serial recurrence from registers; stores stream out.
    f32x4 v = (f32x4)(0.f, 0.f, 0.f, 0.f);
    #pragma unroll
    for (int t = 0; t < PLIF_T; ++t) {
        v += xt[t];

        f32x4 s;
        s.x = (v.x > 1.0f) ? 1.0f : 0.0f;
        s.y = (v.y > 1.0f) ? 1.0f : 0.0f;
        s.z = (v.z > 1.0f) ? 1.0f : 0.0f;
        s.w = (v.w > 1.0f) ? 1.0f : 0.0f;

        v -= s;

        __builtin_nontemporal_store(s, &out[(size_t)t * (size_t)n4 + (size_t)i]);
    }
}

extern "C" void kernel_launch(void* const* d_in, const int* in_sizes, int n_in,
                              void* d_out, int out_size, void* d_ws, size_t ws_size,
                              hipStream_t stream) {
    const float* x = (const float*)d_in[0];
    float* out = (float*)d_out;

    const int total = in_sizes[0];          // T * N
    const int n = total / PLIF_T;           // spatial elements per timestep
    const int n4 = n / 4;                   // float4 groups per timestep

    const int block = 256;
    const int grid = (n4 + block - 1) / block;   // 4096 for reference shape

    plif_fwd_kernel<<<grid, block, 0, stream>>>(
        (const f32x4*)x, (f32x4*)out, n4);
}